// Round 6
// baseline (175.679 us; speedup 1.0000x reference)
//
#include <hip/hip_runtime.h>

//   x        : (B, C, 7, 7) fp32      -> in[0], B*C*49
//   s        : (B, 1, 56, 56) fp32    -> in[1], B*3136
//   feat_mask: (8, 7, 7) fp32         -> in[2], 392
//   sal_idx  : (8, N) int32           -> in[3], 8*N  (N = 406)
// out = [feat (B*C*8) | sal_feat (B*N*8)] fp32
//
// R6: no-LDS design. 4 rows/lane (196 floats = 784 B, 16B-aligned) read as 49
// aligned float4 directly from global; fully unrolled so (row,col) are
// compile-time; masks via wave-uniform s_load; acc[4][8] in VGPRs. Removes the
// stage->drain->transpose structure that pinned R2/R4/R5 at ~56-60 us.

#define KPIX 49
#define RPL 4                 // rows per lane (4*49*4B = 784B, aligned)
#define RPB (64 * RPL)        // 256 rows per one-wave block

__global__ __launch_bounds__(64, 3) void mdp_fused_kernel(
    const float* __restrict__ x, const float* __restrict__ s,
    const float* __restrict__ fm, const int* __restrict__ sidx,
    float* __restrict__ out, int BC, int nb1, int N, int SHW, int qper)
{
    const int lane = threadIdx.x;

    if ((int)blockIdx.x < nb1) {
        // ---- feat path: one wave, 256 rows, 4 rows/lane, zero LDS ----
        // per-direction 1/count via ballot (SGPR-resident)
        float rc[8];
        #pragma unroll
        for (int p = 0; p < 8; ++p) {
            float v = (lane < KPIX) ? fm[p * KPIX + lane] : 0.f;
            unsigned long long bm = __ballot(v != 0.f);
            rc[p] = 1.0f / (float)__popcll(bm);
        }

        const int r0 = blockIdx.x * RPB + lane * RPL;  // this lane's first row
        if (r0 + RPL <= BC) {
            const float4* base = (const float4*)(x + (size_t)r0 * KPIX); // 16B aligned
            float acc[RPL][8];
            #pragma unroll
            for (int rr = 0; rr < RPL; ++rr)
                #pragma unroll
                for (int p = 0; p < 8; ++p) acc[rr][p] = 0.f;

            #pragma unroll
            for (int j = 0; j < KPIX; ++j) {      // 49 independent aligned loads
                const float4 v = base[j];
                #pragma unroll
                for (int c = 0; c < 4; ++c) {
                    const int f   = j * 4 + c;    // 0..195, compile-time
                    const int row = f / KPIX;     // compile-time
                    const int col = f % KPIX;     // compile-time
                    const float e = (c == 0) ? v.x : (c == 1) ? v.y
                                  : (c == 2) ? v.z : v.w;
                    #pragma unroll
                    for (int p = 0; p < 8; ++p)
                        acc[row][p] += e * fm[p * KPIX + col];  // uniform -> s_load
                }
            }

            float4* o = (float4*)(out + (size_t)r0 * 8);  // 128B-aligned per lane
            #pragma unroll
            for (int rr = 0; rr < RPL; ++rr) {
                o[rr * 2 + 0] = make_float4(acc[rr][0] * rc[0], acc[rr][1] * rc[1],
                                            acc[rr][2] * rc[2], acc[rr][3] * rc[3]);
                o[rr * 2 + 1] = make_float4(acc[rr][4] * rc[4], acc[rr][5] * rc[5],
                                            acc[rr][6] * rc[6], acc[rr][7] * rc[7]);
            }
        } else {
            // tail (BC not multiple of 256): scalar per-row fallback
            for (int rr = 0; rr < RPL; ++rr) {
                const int r = r0 + rr;
                if (r >= BC) break;
                float sum[8];
                #pragma unroll
                for (int p = 0; p < 8; ++p) sum[p] = 0.f;
                for (int k = 0; k < KPIX; ++k) {
                    const float e = x[(size_t)r * KPIX + k];
                    #pragma unroll
                    for (int p = 0; p < 8; ++p) sum[p] += e * fm[p * KPIX + k];
                }
                for (int p = 0; p < 8; ++p) out[(size_t)r * 8 + p] = sum[p] * rc[p];
            }
        }
    } else {
        // ---- sal_feat path: qper blocks per batch row ----
        const int bq = blockIdx.x - nb1;
        const int b = bq / qper, q = bq % qper;
        const int tot = N * 8;
        const int chunk = tot / qper;
        const float* srow = s + (size_t)b * SHW;
        float* o2 = out + (size_t)BC * 8 + (size_t)b * tot + (size_t)q * chunk;
        for (int i = lane; i < chunk; i += 64) {
            const int e = q * chunk + i;
            o2[i] = srow[sidx[(e & 7) * N + (e >> 3)]];
        }
    }
}

extern "C" void kernel_launch(void* const* d_in, const int* in_sizes, int n_in,
                              void* d_out, int out_size, void* d_ws, size_t ws_size,
                              hipStream_t stream) {
    const float* x    = (const float*)d_in[0];
    const float* s    = (const float*)d_in[1];
    const float* fm   = (const float*)d_in[2];
    const int*   sidx = (const int*)d_in[3];
    float* out = (float*)d_out;

    const int SHW = 3136;                  // 56*56
    const int B   = in_sizes[1] / SHW;     // 256
    const int BC  = in_sizes[0] / KPIX;    // 524288
    const int N   = in_sizes[3] / 8;       // 406

    const int nb1  = (BC + RPB - 1) / RPB;              // 2048
    const int qper = ((N * 8) % 4 == 0) ? 4 : 1;        // 812-elem chunks
    const int grid = nb1 + B * qper;                    // 2048 + 1024

    mdp_fused_kernel<<<grid, 64, 0, stream>>>(x, s, fm, sidx, out,
                                              BC, nb1, N, SHW, qper);
}